// Round 4
// baseline (1180.522 us; speedup 1.0000x reference)
//
#include <hip/hip_runtime.h>
#include <hip/hip_bf16.h>

#define N_USERS 100000
#define N_ITEMS 150000
#define N_NODES 250000
#define N_EDGES 4000000
#define DIM     64
#define N_ELEM  (N_NODES * DIM)      // 16,000,000
#define U_ELEM  (N_USERS * DIM)      //  6,400,000
#define SCAN_BS 256
#define SCAN_NB ((N_NODES + SCAN_BS - 1) / SCAN_BS)   // 977

struct alignas(8) Edge { int src; float val; };

// ---------------- helpers ----------------
__device__ __forceinline__ void  store_x(float* p, float v)          { *p = v; }
__device__ __forceinline__ void  store_x(__hip_bfloat16* p, float v) { *p = __float2bfloat16(v); }
__device__ __forceinline__ float load_x(const float* p)              { return *p; }
__device__ __forceinline__ float load_x(const __hip_bfloat16* p)     { return __bfloat162float(*p); }

// ---------------- dtype probe (flag=1 -> bf16 inputs, 0 -> fp32) ----------------
__global__ void probe_dtype(const unsigned short* __restrict__ ue, int* __restrict__ flag) {
    int lane = threadIdx.x;   // 64 threads
    int bad = 0;
    #pragma unroll
    for (int k = 0; k < 8; ++k) {
        unsigned int b = ((unsigned int)ue[lane * 8 + k]) << 16;
        float f = fabsf(__uint_as_float(b));
        if (!(f < 1.0f)) bad = 1;
    }
    unsigned long long m = __ballot(bad);
    if (lane == 0) flag[0] = (m == 0ULL) ? 1 : 0;
}

// ---------------- CSR build ----------------
__global__ void hist_kernel(const int* __restrict__ dst, int* __restrict__ row_ptr) {
    int e = blockIdx.x * blockDim.x + threadIdx.x;
    if (e < N_EDGES) atomicAdd(&row_ptr[dst[e] + 1], 1);
}

// inclusive scan of a[0..N_NODES-1] (a = row_ptr+1), per-block stage
__global__ void scan_block(int* __restrict__ a, int* __restrict__ bsums) {
    __shared__ int sh[SCAN_BS];
    int gid = blockIdx.x * SCAN_BS + threadIdx.x;
    sh[threadIdx.x] = (gid < N_NODES) ? a[gid] : 0;
    __syncthreads();
    for (int off = 1; off < SCAN_BS; off <<= 1) {
        int t = (threadIdx.x >= off) ? sh[threadIdx.x - off] : 0;
        __syncthreads();
        sh[threadIdx.x] += t;
        __syncthreads();
    }
    if (gid < N_NODES) a[gid] = sh[threadIdx.x];
    if (threadIdx.x == SCAN_BS - 1) bsums[blockIdx.x] = sh[threadIdx.x];
}

__global__ void scan_tops(int* __restrict__ bsums) {
    __shared__ int sh[1024];
    sh[threadIdx.x] = (threadIdx.x < SCAN_NB) ? bsums[threadIdx.x] : 0;
    __syncthreads();
    for (int off = 1; off < 1024; off <<= 1) {
        int t = (threadIdx.x >= off) ? sh[threadIdx.x - off] : 0;
        __syncthreads();
        sh[threadIdx.x] += t;
        __syncthreads();
    }
    if (threadIdx.x < SCAN_NB) bsums[threadIdx.x] = sh[threadIdx.x];
}

// also initializes cursor[] (absorbs old copy_cursor kernel)
__global__ void finalize_rows(int* __restrict__ row_ptr, const int* __restrict__ bsums,
                              int* __restrict__ cursor) {
    int i = blockIdx.x * blockDim.x + threadIdx.x;   // element i of a[] == row_ptr[i+1]
    if (i >= N_NODES) return;
    int b = i / SCAN_BS;
    int v = row_ptr[i + 1];
    if (b > 0) v += bsums[b - 1];
    row_ptr[i + 1] = v;
    if (i + 1 < N_NODES) cursor[i + 1] = v;
    if (i == 0) { row_ptr[0] = 0; cursor[0] = 0; }
}

// single 8-byte paired store per edge
__global__ void scatter_kernel(const int* __restrict__ src, const int* __restrict__ dst,
                               const void* __restrict__ valsv, const int* __restrict__ flag,
                               int* __restrict__ cursor, Edge* __restrict__ sedge) {
    int e = blockIdx.x * blockDim.x + threadIdx.x;
    if (e >= N_EDGES) return;
    int d = dst[e];
    int pos = atomicAdd(&cursor[d], 1);
    float v = (*flag) ? __bfloat162float(((const __hip_bfloat16*)valsv)[e])
                      : ((const float*)valsv)[e];
    Edge ed; ed.src = src[e]; ed.val = v;
    sedge[pos] = ed;
}

// ---------------- init: x = concat(user,item); acc (T1) or out-acc (T2/T3) ----------------
template <typename XT>
__global__ void init_kernel(const void* __restrict__ uev, const void* __restrict__ iev,
                            const int* __restrict__ flag,
                            XT* __restrict__ x,
                            float* __restrict__ acc,
                            void* __restrict__ outacc) {
    int i = blockIdx.x * blockDim.x + threadIdx.x;
    if (i >= N_ELEM) return;
    const int isbf = *flag;
    float v;
    if (i < U_ELEM) {
        v = isbf ? __bfloat162float(((const __hip_bfloat16*)uev)[i]) : ((const float*)uev)[i];
    } else {
        int j = i - U_ELEM;
        v = isbf ? __bfloat162float(((const __hip_bfloat16*)iev)[j]) : ((const float*)iev)[j];
    }
    store_x(&x[i], v);
    if (acc) acc[i] = v;
    if (outacc) {
        if (isbf) ((__hip_bfloat16*)outacc)[i] = __float2bfloat16(0.25f * v);
        else      ((float*)outacc)[i]          = 0.25f * v;
    }
}

// ---------------- CSR SpMM: one wave per dst node, lane = dim ----------------
template <typename XT>
__global__ void spmm_csr(const int* __restrict__ row_ptr,
                         const Edge* __restrict__ sedge,
                         const XT* __restrict__ x,
                         XT* __restrict__ xn,
                         float* __restrict__ acc,      // T1 mode if non-null
                         void* __restrict__ outv,      // T2/T3 RMW target, or T1 final target
                         const int* __restrict__ flag,
                         int last) {
    int lane = threadIdx.x & 63;
    int w = (blockIdx.x * blockDim.x + threadIdx.x) >> 6;
    if (w >= N_NODES) return;
    int beg = row_ptr[w], end = row_ptr[w + 1];
    float s = 0.f;
    int e = beg;
    for (; e + 4 <= end; e += 4) {
        Edge e0 = sedge[e], e1 = sedge[e + 1], e2 = sedge[e + 2], e3 = sedge[e + 3];
        float a0 = load_x(&x[(size_t)e0.src * DIM + lane]);
        float a1 = load_x(&x[(size_t)e1.src * DIM + lane]);
        float a2 = load_x(&x[(size_t)e2.src * DIM + lane]);
        float a3 = load_x(&x[(size_t)e3.src * DIM + lane]);
        s += e0.val * a0; s += e1.val * a1; s += e2.val * a2; s += e3.val * a3;
    }
    for (; e < end; ++e) {
        Edge ee = sedge[e];
        s += ee.val * load_x(&x[(size_t)ee.src * DIM + lane]);
    }

    size_t o = (size_t)w * DIM + lane;
    if (acc) {
        if (!last) {
            store_x(&xn[o], s);
            acc[o] += s;
        } else {
            float r = 0.25f * (acc[o] + s);
            if (*flag) ((__hip_bfloat16*)outv)[o] = __float2bfloat16(r);
            else       ((float*)outv)[o]          = r;
        }
    } else {
        if (!last) store_x(&xn[o], s);
        if (*flag) {
            __hip_bfloat16* ob = (__hip_bfloat16*)outv;
            ob[o] = __float2bfloat16(__bfloat162float(ob[o]) + 0.25f * s);
        } else {
            float* of = (float*)outv;
            of[o] += 0.25f * s;
        }
    }
}

// ---------------- host ----------------
static inline size_t align256(size_t x) { return (x + 255) & ~(size_t)255; }

extern "C" void kernel_launch(void* const* d_in, const int* in_sizes, int n_in,
                              void* d_out, int out_size, void* d_ws, size_t ws_size,
                              hipStream_t stream) {
    const int* es = (const int*)d_in[3];
    const int* ed = (const int*)d_in[4];

    char* wsb = (char*)d_ws;
    size_t off = 0;
    int* flag    = (int*)wsb;                 off = align256(off + sizeof(int));
    int* row_ptr = (int*)(wsb + off);         off = align256(off + (size_t)(N_NODES + 1) * 4);
    int* cursor  = (int*)(wsb + off);         off = align256(off + (size_t)N_NODES * 4);
    int* bsums   = (int*)(wsb + off);         off = align256(off + (size_t)SCAN_NB * 4);
    Edge* sedge  = (Edge*)(wsb + off);        off = align256(off + (size_t)N_EDGES * sizeof(Edge));
    size_t buf_off = off;

    const size_t f32buf = (size_t)N_ELEM * sizeof(float);          // 64 MB
    const size_t bfbuf  = (size_t)N_ELEM * sizeof(__hip_bfloat16); // 32 MB

    const int eb = 256;
    const int egrid = (N_ELEM + eb - 1) / eb;
    const int ggrid = (N_EDGES + eb - 1) / eb;            // 15625
    const int ngrid = (N_NODES + eb - 1) / eb;            // 977
    const int sgrid = (N_NODES + 3) / 4;                  // 62500 blocks, 4 waves each

    // ---- prologue: probe + CSR build ----
    probe_dtype<<<1, 64, 0, stream>>>((const unsigned short*)d_in[0], flag);
    hipMemsetAsync(row_ptr, 0, (size_t)(N_NODES + 1) * 4, stream);
    hist_kernel<<<ggrid, eb, 0, stream>>>(ed, row_ptr);
    scan_block<<<SCAN_NB, SCAN_BS, 0, stream>>>(row_ptr + 1, bsums);
    scan_tops<<<1, 1024, 0, stream>>>(bsums);
    finalize_rows<<<ngrid, eb, 0, stream>>>(row_ptr, bsums, cursor);
    scatter_kernel<<<ggrid, eb, 0, stream>>>(es, ed, d_in[2], flag, cursor, sedge);

    size_t need_t1 = buf_off + 3 * f32buf;   // ~226 MB
    size_t need_t2 = buf_off + 2 * f32buf;   // ~162 MB

    if (ws_size >= need_t1) {
        // T1: fp32 x, xn, acc; out written by last spmm
        float* x   = (float*)(wsb + buf_off);
        float* xn  = x + N_ELEM;
        float* acc = xn + N_ELEM;
        init_kernel<float><<<egrid, eb, 0, stream>>>(d_in[0], d_in[1], flag, x, acc, nullptr);
        spmm_csr<float><<<sgrid, eb, 0, stream>>>(row_ptr, sedge, x,  xn, acc, nullptr, flag, 0);
        spmm_csr<float><<<sgrid, eb, 0, stream>>>(row_ptr, sedge, xn, x,  acc, nullptr, flag, 0);
        spmm_csr<float><<<sgrid, eb, 0, stream>>>(row_ptr, sedge, x,  xn, acc, d_out,   flag, 1);
    } else if (ws_size >= need_t2) {
        // T2: fp32 x, xn; accumulate into d_out (RMW)
        float* x  = (float*)(wsb + buf_off);
        float* xn = x + N_ELEM;
        init_kernel<float><<<egrid, eb, 0, stream>>>(d_in[0], d_in[1], flag, x, nullptr, d_out);
        spmm_csr<float><<<sgrid, eb, 0, stream>>>(row_ptr, sedge, x,  xn, nullptr, d_out, flag, 0);
        spmm_csr<float><<<sgrid, eb, 0, stream>>>(row_ptr, sedge, xn, x,  nullptr, d_out, flag, 0);
        spmm_csr<float><<<sgrid, eb, 0, stream>>>(row_ptr, sedge, x,  xn, nullptr, d_out, flag, 1);
    } else {
        // T3: bf16 x, xn; accumulate into d_out (RMW)
        __hip_bfloat16* x  = (__hip_bfloat16*)(wsb + buf_off);
        __hip_bfloat16* xn = x + N_ELEM;
        init_kernel<__hip_bfloat16><<<egrid, eb, 0, stream>>>(d_in[0], d_in[1], flag, x, nullptr, d_out);
        spmm_csr<__hip_bfloat16><<<sgrid, eb, 0, stream>>>(row_ptr, sedge, x,  xn, nullptr, d_out, flag, 0);
        spmm_csr<__hip_bfloat16><<<sgrid, eb, 0, stream>>>(row_ptr, sedge, xn, x,  nullptr, d_out, flag, 0);
        spmm_csr<__hip_bfloat16><<<sgrid, eb, 0, stream>>>(row_ptr, sedge, x,  xn, nullptr, d_out, flag, 1);
    }
}